// Round 1
// 1312.610 us; speedup vs baseline: 1.2944x; 1.2944x over previous
//
#include <hip/hip_runtime.h>
#include <hip/hip_bf16.h>
#include <cstdio>
#include <cstdint>

#define BATCH 32
#define SEQ 512
#define BSQ (BATCH*SEQ)      // 16384
#define HIDD 300
#define HD 64
#define NHEAD 8
#define DHEAD 8
#define NLAYERS 6
#define FFD 1200
#define NCLS 1000

typedef short short8 __attribute__((ext_vector_type(8)));
typedef float floatx4 __attribute__((ext_vector_type(4)));

__device__ __forceinline__ short f2b(float v){
  __hip_bfloat16 h = __float2bfloat16(v);
  short s; __builtin_memcpy(&s, &h, 2); return s;
}

// ------- embedding + positional encoding -> acc = 2*emb + pos (fp32 + bf16) -
// grid covers BSQ*320: cols 300..319 zero-pad the bf16 copy only.
__global__ void t10_embed(const int* __restrict__ toks,
                          const float* __restrict__ emb,
                          float* __restrict__ acc,
                          short* __restrict__ accbf){
  int idx = blockIdx.x*256 + threadIdx.x;
  if (idx >= BSQ*320) return;
  int row = idx / 320;
  int j   = idx - row*320;
  if (j >= HIDD){ accbf[(size_t)row*320 + j] = 0; return; }
  int t = toks[row];
  float e = emb[(size_t)t*HIDD + j];
  int s = row & (SEQ-1);
  float expo = (float)(j & ~1) * (1.0f/(float)HIDD);
  float ang  = (float)s * expf(-expo * 9.210340371976184f);
  float pe   = (j & 1) ? cosf(ang) : sinf(ang);
  float v = 2.0f*e + pe;
  acc[(size_t)row*HIDD + j] = v;
  accbf[(size_t)row*320 + j] = f2b(v);
}

// ------- weight prep: fp32 [K][N] -> bf16 transposed [Npad][Kpad] -----------
// perm: dest col n takes source col (n&7)*8 + (n>>3)  (head-major reorder)
__global__ void prep_w(const float* __restrict__ src, short* __restrict__ dst,
                       int K, int N, int Kpad, int rows, int nbase,
                       int sls, int dls, int total, int perm){
  int idx = blockIdx.x*256 + threadIdx.x;
  if (idx >= total) return;
  int l   = idx / (rows*Kpad);
  int rem = idx - l*(rows*Kpad);
  int n = rem / Kpad;
  int k = rem - n*Kpad;
  int sc = perm ? ((n & 7)*8 + (n >> 3)) : n;
  float v = (n < N && k < K) ? src[(size_t)l*sls + (size_t)k*N + sc] : 0.f;
  dst[(size_t)l*dls + (size_t)(nbase+n)*Kpad + k] = f2b(v);
}

// ---- bf16 MFMA GEMM: C[M,N](f32) or Cb[M,Npad](bf16) = A[M,Kpad](bf16) @ Wt
// A is pre-converted, zero-padded bf16.  1-D grid with XCD-bijective swizzle:
// each XCD gets a contiguous chunk of m-tiles (n-fastest inside) so all
// n-blocks sharing an A-tile hit the same XCD L2.
__global__ __launch_bounds__(256) void mm_a16(
    const short* __restrict__ A, const short* __restrict__ Wt,
    const float* __restrict__ bias, float* __restrict__ C,
    short* __restrict__ Cb,
    int M, int N, int Kpad, int Npad, int nnb, int relu){
  __shared__ short sA[64][40];
  __shared__ short sB[64][40];
  int wg = blockIdx.x;
  int cpx = gridDim.x >> 3;                 // nwg is always a multiple of 8
  int swz = (wg & 7)*cpx + (wg >> 3);
  int mt = swz / nnb, nt = swz - mt*nnb;
  int m0 = mt*64, n0 = nt*64;
  int tid = threadIdx.x;
  int lane = tid & 63, wv = tid >> 6;
  int wm = (wv & 1)*32, wn = (wv >> 1)*32;
  int l15 = lane & 15, quad = lane >> 4;
  floatx4 acc[2][2] = {};
  int srow = tid >> 2, sko = (tid & 3)*8;
  const short* Arow = A  + (size_t)(m0 + srow)*Kpad + sko;
  const short* Brow = Wt + (size_t)(n0 + srow)*Kpad + sko;
  int nch = Kpad >> 5;
  for (int c = 0; c < nch; c++){
    int k0 = c*32;
    __syncthreads();
    *(short8*)&sA[srow][sko] = *(const short8*)(Arow + k0);
    *(short8*)&sB[srow][sko] = *(const short8*)(Brow + k0);
    __syncthreads();
    short8 af[2], bf[2];
    for (int i=0;i<2;i++)
      af[i] = *(const short8*)&sA[wm + i*16 + l15][quad*8];
    for (int j=0;j<2;j++)
      bf[j] = *(const short8*)&sB[wn + j*16 + l15][quad*8];
    for (int i=0;i<2;i++)
      for (int j=0;j<2;j++)
        acc[i][j] = __builtin_amdgcn_mfma_f32_16x16x32_bf16(af[i], bf[j], acc[i][j], 0,0,0);
  }
  if (Cb){
    for (int j=0;j<2;j++){
      int n = n0 + wn + j*16 + l15;
      float bv = (bias && n < N) ? bias[n] : 0.f;
      for (int i=0;i<2;i++){
        int mbase = m0 + wm + i*16 + quad*4;
        for (int r=0;r<4;r++){
          float cv = acc[i][j][r] + bv;
          if (relu) cv = fmaxf(cv, 0.f);
          Cb[(size_t)(mbase+r)*Npad + n] = (n < N) ? f2b(cv) : (short)0;
        }
      }
    }
  } else {
    for (int j=0;j<2;j++){
      int n = n0 + wn + j*16 + l15;
      if (n >= N) continue;
      float bv = bias ? bias[n] : 0.f;
      for (int i=0;i<2;i++){
        int mbase = m0 + wm + i*16 + quad*4;
        for (int r=0;r<4;r++){
          float cv = acc[i][j][r] + bv;
          if (relu) cv = fmaxf(cv, 0.f);
          C[(size_t)(mbase+r)*N + n] = cv;
        }
      }
    }
  }
}

// ---- attention: head-major qkv [BSQ][192]; block=(b,h); thread = 2 queries -
// output written directly as bf16 (identical value to the old f2b-in-GEMM).
__global__ __launch_bounds__(256) void t11_attn(
    const float* __restrict__ qkv, const int* __restrict__ toks,
    short* __restrict__ aout){
  __shared__ float kb[SEQ][8];
  __shared__ float vb[SEQ][8];
  __shared__ float msk[SEQ];
  int bh = blockIdx.x;
  int b = bh >> 3, h = bh & 7;
  int tid = threadIdx.x;
  for (int idx = tid; idx < SEQ*2; idx += 256){
    int r = idx >> 1, half = (idx & 1)*4;
    const float* src = qkv + (size_t)(b*SEQ+r)*192 + h*8 + half;
    *(float4*)&kb[r][half] = *(const float4*)(src + 64);
    *(float4*)&vb[r][half] = *(const float4*)(src + 128);
  }
  for (int s2 = tid; s2 < SEQ; s2 += 256)
    msk[s2] = (toks[b*SEQ+s2]==0) ? -1e9f : 0.f;
  __syncthreads();
  const float scale = 0.057735026918962574f;  // 1/sqrt(300)
  float q0[8], q1[8];
  {
    const float* s0 = qkv + (size_t)(b*SEQ+tid)*192 + h*8;
    const float* s1 = qkv + (size_t)(b*SEQ+tid+256)*192 + h*8;
    *(float4*)&q0[0] = *(const float4*)s0; *(float4*)&q0[4] = *(const float4*)(s0+4);
    *(float4*)&q1[0] = *(const float4*)s1; *(float4*)&q1[4] = *(const float4*)(s1+4);
  }
  float sum0=0.f, sum1=0.f, o0[8]={}, o1[8]={};
  for (int k=0; k<SEQ; k++){
    float kr[8], vr[8];
    *(float4*)&kr[0] = *(float4*)&kb[k][0]; *(float4*)&kr[4] = *(float4*)&kb[k][4];
    *(float4*)&vr[0] = *(float4*)&vb[k][0]; *(float4*)&vr[4] = *(float4*)&vb[k][4];
    float s0v=0.f, s1v=0.f;
    for (int d=0; d<8; d++){ s0v = fmaf(q0[d],kr[d],s0v); s1v = fmaf(q1[d],kr[d],s1v); }
    float m = msk[k];
    float p0 = __expf(fminf(fmaf(s0v,scale,m), 60.f));   // masked: ~-1e9 -> exp = 0
    float p1 = __expf(fminf(fmaf(s1v,scale,m), 60.f));
    sum0 += p0; sum1 += p1;
    for (int d=0; d<8; d++){ o0[d] = fmaf(p0,vr[d],o0[d]); o1[d] = fmaf(p1,vr[d],o1[d]); }
  }
  float i0 = 1.f/sum0, i1 = 1.f/sum1;
  short8 r0b, r1b;
  for (int d=0;d<8;d++){ r0b[d]=f2b(o0[d]*i0); r1b[d]=f2b(o1[d]*i1); }
  *(short8*)(aout + (size_t)(b*SEQ+tid)*HD + h*8) = r0b;
  *(short8*)(aout + (size_t)(b*SEQ+tid+256)*HD + h*8) = r1b;
}

// ---- fused residual add + LayerNorm (ddof=1); optional bf16 copy + acc+= ---
__global__ __launch_bounds__(256) void t10_addnorm(
                 const float* __restrict__ xa, const float* __restrict__ xb,
                 float* __restrict__ y, short* __restrict__ ybf,
                 float* __restrict__ accum, short* __restrict__ accbf,
                 const float* __restrict__ gamma, const float* __restrict__ beta,
                 int l){
  __shared__ float red[8];
  int row = blockIdx.x, tid = threadIdx.x;
  size_t base = (size_t)row*HIDD;
  size_t bbase = (size_t)row*320;
  float v0 = xa[base+tid] + xb[base+tid];
  float v1 = 0.f;
  int has1 = (tid+256 < HIDD);
  if (has1) v1 = xa[base+tid+256] + xb[base+tid+256];
  float s = v0+v1, sq = v0*v0+v1*v1;
  for (int off=32; off; off>>=1){ s += __shfl_down(s,off); sq += __shfl_down(sq,off); }
  int lane = tid & 63, w = tid >> 6;
  if (lane==0){ red[w]=s; red[4+w]=sq; }
  __syncthreads();
  float sum = red[0]+red[1]+red[2]+red[3];
  float ssq = red[4]+red[5]+red[6]+red[7];
  float mu  = sum * (1.0f/HIDD);
  float var = (ssq - (float)HIDD*mu*mu) * (1.0f/(HIDD-1));
  float rstd = rsqrtf(var + 1e-8f);
  float g = gamma[l], be = beta[l];
  float o0 = g*(v0-mu)*rstd + be;
  y[base+tid] = o0;
  if (ybf) ybf[bbase+tid] = f2b(o0);
  if (accum){
    float a0 = accum[base+tid] + o0;
    accum[base+tid] = a0;
    if (accbf) accbf[bbase+tid] = f2b(a0);
  }
  if (has1){
    float o1 = g*(v1-mu)*rstd + be;
    y[base+tid+256] = o1;
    if (ybf) ybf[bbase+tid+256] = f2b(o1);
    if (accum){
      float a1 = accum[base+tid+256] + o1;
      accum[base+tid+256] = a1;
      if (accbf) accbf[bbase+tid+256] = f2b(a1);
    }
  } else if (tid+256 < 320){
    if (ybf) ybf[bbase+tid+256] = 0;
    if (accbf) accbf[bbase+tid+256] = 0;
  }
}

// ---------------- fp32 tiled GEMM (classifier only, M=32) -------------------
#define GBM 64
#define GBN 64
#define GBK 16
__global__ __launch_bounds__(256) void t9_gemm(
                 const float* __restrict__ A, const float* __restrict__ W,
                 const float* __restrict__ bias, float* __restrict__ C,
                 int M, int N, int K, int relu){
  __shared__ float sA[GBM][GBK+1];
  __shared__ float sW[GBK][GBN];
  int tid = threadIdx.x;
  int tx = tid & 15, ty = tid >> 4;
  int m0 = blockIdx.y * GBM, n0 = blockIdx.x * GBN;
  float cacc[4][4] = {};
  int lr = tid >> 4, lk = tid & 15;
  int lc = tid & 63, lkb = tid >> 6;
  for (int k0 = 0; k0 < K; k0 += GBK){
    for (int t = 0; t < 4; t++){
      int row = lr + t*16;
      float vv = 0.f;
      int gm = m0 + row, gk = k0 + lk;
      if (gm < M && gk < K) vv = A[(size_t)gm*K + gk];
      sA[row][lk] = vv;
    }
    for (int t = 0; t < 4; t++){
      int kk = lkb + t*4;
      float vv = 0.f;
      int gk = k0 + kk, gn = n0 + lc;
      if (gk < K && gn < N) vv = W[(size_t)gk*N + gn];
      sW[kk][lc] = vv;
    }
    __syncthreads();
    for (int kk = 0; kk < GBK; kk++){
      float a0[4], b0[4];
      for (int i=0;i<4;i++) a0[i] = sA[ty*4+i][kk];
      for (int j=0;j<4;j++) b0[j] = sW[kk][tx*4+j];
      for (int i=0;i<4;i++)
        for (int j=0;j<4;j++)
          cacc[i][j] = fmaf(a0[i], b0[j], cacc[i][j]);
    }
    __syncthreads();
  }
  for (int i=0;i<4;i++){
    int m = m0 + ty*4 + i;
    if (m >= M) continue;
    for (int j=0;j<4;j++){
      int n = n0 + tx*4 + j;
      if (n >= N) continue;
      float cv = cacc[i][j];
      if (bias) cv += bias[n];
      if (relu) cv = fmaxf(cv, 0.f);
      C[(size_t)m*N + n] = cv;
    }
  }
}

// ---------------- sum over sequence: (B,S,HID) -> (B,HID) -------------------
__global__ void t10_colsum(const float* __restrict__ outb, float* __restrict__ sums){
  int b = blockIdx.x, j = threadIdx.x;
  if (j >= HIDD) return;
  float s = 0.f;
  size_t base = (size_t)b*SEQ*HIDD;
  for (int t=0; t<SEQ; t++) s += outb[base + (size_t)t*HIDD + j];
  sums[b*HIDD + j] = s;
}

// ---------------- classifier head: LayerNorm(ddof=1) + softmax -> fp32 -----
__device__ __forceinline__ float t10_bsum(float val, float* red){
  for (int off=32; off; off>>=1) val += __shfl_down(val, off);
  __syncthreads();
  if ((threadIdx.x & 63)==0) red[threadIdx.x>>6] = val;
  __syncthreads();
  return red[0]+red[1]+red[2]+red[3];
}
__device__ __forceinline__ float t10_bmax(float val, float* red){
  for (int off=32; off; off>>=1) val = fmaxf(val, __shfl_down(val, off));
  __syncthreads();
  if ((threadIdx.x & 63)==0) red[threadIdx.x>>6] = val;
  __syncthreads();
  return fmaxf(fmaxf(red[0],red[1]), fmaxf(red[2],red[3]));
}

__global__ __launch_bounds__(256) void t10_final(
                  const float* __restrict__ logits,
                  const float* __restrict__ gf, const float* __restrict__ bff,
                  float* __restrict__ outp){
  __shared__ float red[4];
  int b = blockIdx.x, tid = threadIdx.x;
  size_t base = (size_t)b*NCLS;
  float v[4];
  float s = 0.f, sq = 0.f;
  for (int t=0;t<4;t++){
    int j = tid + t*256;
    float x = (j < NCLS) ? logits[base+j] : 0.f;
    v[t] = x; s += x; sq += x*x;
  }
  s  = t10_bsum(s, red);
  sq = t10_bsum(sq, red);
  float mu  = s * (1.0f/NCLS);
  float var = (sq - (float)NCLS*mu*mu) * (1.0f/(NCLS-1));
  float rstd = rsqrtf(var + 1e-8f);
  float g = gf[0], be = bff[0];
  float y[4]; float mx = -1e30f;
  for (int t=0;t<4;t++){
    int j = tid + t*256;
    y[t] = g*(v[t]-mu)*rstd + be;
    if (j < NCLS) mx = fmaxf(mx, y[t]);
  }
  mx = t10_bmax(mx, red);
  float p[4]; float es = 0.f;
  for (int t=0;t<4;t++){
    int j = tid + t*256;
    p[t] = (j < NCLS) ? __expf(y[t]-mx) : 0.f;
    es += p[t];
  }
  es = t10_bsum(es, red);
  float inv = 1.0f/es;
  for (int t=0;t<4;t++){
    int j = tid + t*256;
    if (j < NCLS) outp[base+j] = p[t]*inv;
  }
}

// ---------------------------------------------------------------------------
extern "C" void kernel_launch(void* const* d_in, const int* in_sizes, int n_in,
                              void* d_out, int out_size, void* d_ws, size_t ws_size,
                              hipStream_t stream){
  const int*   toks = (const int*)d_in[0];
  const float* emb  = (const float*)d_in[1];
  const float* WQ   = (const float*)d_in[2];
  const float* WK   = (const float*)d_in[3];
  const float* WV   = (const float*)d_in[4];
  const float* WO   = (const float*)d_in[5];
  const float* W1   = (const float*)d_in[6];
  const float* b1   = (const float*)d_in[7];
  const float* W2   = (const float*)d_in[8];
  const float* b2   = (const float*)d_in[9];
  const float* g1   = (const float*)d_in[10];
  const float* be1  = (const float*)d_in[11];
  const float* g2   = (const float*)d_in[12];
  const float* be2  = (const float*)d_in[13];
  const float* Vd   = (const float*)d_in[14];
  const float* gf   = (const float*)d_in[15];
  const float* bff  = (const float*)d_in[16];
  float* outp = (float*)d_out;

  // fp32 buffers
  float* acc    = (float*)d_ws;                         // [BSQ][300]
  float* xn     = acc    + (size_t)BSQ*HIDD;            // [BSQ][300]
  float* outb   = xn     + (size_t)BSQ*HIDD;            // [BSQ][300]
  float* tmp    = outb   + (size_t)BSQ*HIDD;            // [BSQ][300]
  float* qkv    = tmp    + (size_t)BSQ*HIDD;            // [BSQ][192]
  float* sums   = qkv    + (size_t)BSQ*192;             // [32][300]
  float* logits = sums   + BATCH*HIDD;                  // [32][1000]
  // bf16 buffers
  short* acc_bf = (short*)(logits + BATCH*NCLS);        // [BSQ][320]
  short* xn_bf  = acc_bf + (size_t)BSQ*320;             // [BSQ][320]
  short* aat_bf = xn_bf  + (size_t)BSQ*320;             // [BSQ][64]
  short* ff1_bf = aat_bf + (size_t)BSQ*64;              // [BSQ][1216]
  // bf16 weights
  short* wqkv = ff1_bf + (size_t)BSQ*1216;              // [6][192][320]
  short* wo   = wqkv + (size_t)6*192*320;               // [6][320][64]
  short* w1t  = wo   + (size_t)6*320*64;                // [6][1216][320]
  short* w2t  = w1t  + (size_t)6*1216*320;              // [6][320][1216]

  {
    int tq = 6*64*320;
    prep_w<<<(tq+255)/256,256,0,stream>>>(WQ, wqkv, 300, 64, 320, 64, 0,   19200, 61440, tq, 1);
    prep_w<<<(tq+255)/256,256,0,stream>>>(WK, wqkv, 300, 64, 320, 64, 64,  19200, 61440, tq, 1);
    prep_w<<<(tq+255)/256,256,0,stream>>>(WV, wqkv, 300, 64, 320, 64, 128, 19200, 61440, tq, 1);
    int to = 6*320*64;
    prep_w<<<(to+255)/256,256,0,stream>>>(WO, wo, 64, 300, 64, 320, 0, 19200, 20480, to, 0);
    int t1 = 6*1216*320;
    prep_w<<<(t1+255)/256,256,0,stream>>>(W1, w1t, 300, 1200, 320, 1216, 0, 360000, 389120, t1, 0);
    int t2 = 6*320*1216;
    prep_w<<<(t2+255)/256,256,0,stream>>>(W2, w2t, 1200, 300, 1216, 320, 0, 360000, 389120, t2, 0);
  }

  t10_embed<<<(BSQ*320+255)/256, 256, 0, stream>>>(toks, emb, acc, acc_bf);

  for (int l = 0; l < NLAYERS; l++){
    // QKV: [BSQ][320]bf16 @ [192][320] -> qkv fp32 [BSQ][192]
    mm_a16<<<256*3,256,0,stream>>>(acc_bf, wqkv + (size_t)l*61440, nullptr, qkv, nullptr,
                                   BSQ, 192, 320, 0, 3, 0);
    t11_attn<<<BATCH*NHEAD, 256, 0, stream>>>(qkv, toks, aat_bf);
    // WO: [BSQ][64]bf16 @ [320][64] -> tmp fp32 [BSQ][300]
    mm_a16<<<256*5,256,0,stream>>>(aat_bf, wo + (size_t)l*20480, nullptr, tmp, nullptr,
                                   BSQ, 300, 64, 0, 5, 0);
    t10_addnorm<<<BSQ,256,0,stream>>>(tmp, acc, xn, xn_bf, nullptr, nullptr, g1, be1, l);
    // FF1: [BSQ][320]bf16 @ [1216][320] -> ff1 bf16 [BSQ][1216] (bias+relu)
    mm_a16<<<256*19,256,0,stream>>>(xn_bf, w1t + (size_t)l*389120, b1 + (size_t)l*FFD,
                                    nullptr, ff1_bf, BSQ, 1200, 320, 1216, 19, 1);
    // FF2: [BSQ][1216]bf16 @ [320][1216] -> tmp fp32 [BSQ][300] (bias)
    mm_a16<<<256*5,256,0,stream>>>(ff1_bf, w2t + (size_t)l*389120, b2 + (size_t)l*HIDD,
                                   tmp, nullptr, BSQ, 300, 1216, 0, 5, 0);
    t10_addnorm<<<BSQ,256,0,stream>>>(tmp, xn, outb, nullptr, acc, acc_bf, g2, be2, l);
  }

  t10_colsum<<<BATCH, 320, 0, stream>>>(outb, sums);
  t9_gemm<<<dim3((NCLS+GBN-1)/GBN, 1),256,0,stream>>>(sums, Vd, nullptr, logits, BATCH, NCLS, HIDD, 0);
  t10_final<<<BATCH, 256, 0, stream>>>(logits, gf, bff, outp);

  hipStreamCaptureStatus cs = hipStreamCaptureStatusNone;
  hipStreamIsCapturing(stream, &cs);
  if (cs == hipStreamCaptureStatusNone){
    hipError_t e_sync = hipStreamSynchronize(stream);
    float ho[4] = {-1,-1,-1,-1};
    hipMemcpy(ho, d_out, 16, hipMemcpyDeviceToHost);
    fprintf(stderr, "[t11] sync=%s out[0..3]=%g,%g,%g,%g\n",
            hipGetErrorString(e_sync), ho[0], ho[1], ho[2], ho[3]);
    fflush(stderr);
  }
}

// Round 3
// 1277.316 us; speedup vs baseline: 1.3301x; 1.0276x over previous
//
#include <hip/hip_runtime.h>
#include <hip/hip_bf16.h>
#include <cstdio>
#include <cstdint>

#define BATCH 32
#define SEQ 512
#define BSQ (BATCH*SEQ)      // 16384
#define HIDD 300
#define HD 64
#define NHEAD 8
#define DHEAD 8
#define NLAYERS 6
#define FFD 1200
#define NCLS 1000
#define NSPLIT 4
#define KCH (SEQ/NSPLIT)     // 128 keys per block

typedef short short8 __attribute__((ext_vector_type(8)));
typedef float floatx4 __attribute__((ext_vector_type(4)));

__device__ __forceinline__ short f2b(float v){
  __hip_bfloat16 h = __float2bfloat16(v);
  short s; __builtin_memcpy(&s, &h, 2); return s;
}

// ------- embedding + positional encoding -> acc = 2*emb + pos (fp32 + bf16) -
// grid covers BSQ*320: cols 300..319 zero-pad the bf16 copy only.
__global__ void t10_embed(const int* __restrict__ toks,
                          const float* __restrict__ emb,
                          float* __restrict__ acc,
                          short* __restrict__ accbf){
  int idx = blockIdx.x*256 + threadIdx.x;
  if (idx >= BSQ*320) return;
  int row = idx / 320;
  int j   = idx - row*320;
  if (j >= HIDD){ accbf[(size_t)row*320 + j] = 0; return; }
  int t = toks[row];
  float e = emb[(size_t)t*HIDD + j];
  int s = row & (SEQ-1);
  float expo = (float)(j & ~1) * (1.0f/(float)HIDD);
  float ang  = (float)s * expf(-expo * 9.210340371976184f);
  float pe   = (j & 1) ? cosf(ang) : sinf(ang);
  float v = 2.0f*e + pe;
  acc[(size_t)row*HIDD + j] = v;
  accbf[(size_t)row*320 + j] = f2b(v);
}

// ------- weight prep: fp32 [K][N] -> bf16 transposed [Npad][Kpad] -----------
// perm: dest col n takes source col (n&7)*8 + (n>>3)  (head-major reorder)
__global__ void prep_w(const float* __restrict__ src, short* __restrict__ dst,
                       int K, int N, int Kpad, int rows, int nbase,
                       int sls, int dls, int total, int perm){
  int idx = blockIdx.x*256 + threadIdx.x;
  if (idx >= total) return;
  int l   = idx / (rows*Kpad);
  int rem = idx - l*(rows*Kpad);
  int n = rem / Kpad;
  int k = rem - n*Kpad;
  int sc = perm ? ((n & 7)*8 + (n >> 3)) : n;
  float v = (n < N && k < K) ? src[(size_t)l*sls + (size_t)k*N + sc] : 0.f;
  dst[(size_t)l*dls + (size_t)(nbase+n)*Kpad + k] = f2b(v);
}

// ---- bf16 MFMA GEMM: C[M,N](f32) or Cb[M,Npad](bf16) = A[M,Kpad](bf16) @ Wt
// A is pre-converted, zero-padded bf16.  1-D grid with XCD-bijective swizzle:
// each XCD gets a contiguous chunk of m-tiles (n-fastest inside) so all
// n-blocks sharing an A-tile hit the same XCD L2.
__global__ __launch_bounds__(256) void mm_a16(
    const short* __restrict__ A, const short* __restrict__ Wt,
    const float* __restrict__ bias, float* __restrict__ C,
    short* __restrict__ Cb,
    int M, int N, int Kpad, int Npad, int nnb, int relu){
  __shared__ short sA[64][40];
  __shared__ short sB[64][40];
  int wg = blockIdx.x;
  int cpx = gridDim.x >> 3;                 // nwg is always a multiple of 8
  int swz = (wg & 7)*cpx + (wg >> 3);
  int mt = swz / nnb, nt = swz - mt*nnb;
  int m0 = mt*64, n0 = nt*64;
  int tid = threadIdx.x;
  int lane = tid & 63, wv = tid >> 6;
  int wm = (wv & 1)*32, wn = (wv >> 1)*32;
  int l15 = lane & 15, quad = lane >> 4;
  floatx4 acc[2][2] = {};
  int srow = tid >> 2, sko = (tid & 3)*8;
  const short* Arow = A  + (size_t)(m0 + srow)*Kpad + sko;
  const short* Brow = Wt + (size_t)(n0 + srow)*Kpad + sko;
  int nch = Kpad >> 5;
  for (int c = 0; c < nch; c++){
    int k0 = c*32;
    __syncthreads();
    *(short8*)&sA[srow][sko] = *(const short8*)(Arow + k0);
    *(short8*)&sB[srow][sko] = *(const short8*)(Brow + k0);
    __syncthreads();
    short8 af[2], bf[2];
    for (int i=0;i<2;i++)
      af[i] = *(const short8*)&sA[wm + i*16 + l15][quad*8];
    for (int j=0;j<2;j++)
      bf[j] = *(const short8*)&sB[wn + j*16 + l15][quad*8];
    for (int i=0;i<2;i++)
      for (int j=0;j<2;j++)
        acc[i][j] = __builtin_amdgcn_mfma_f32_16x16x32_bf16(af[i], bf[j], acc[i][j], 0,0,0);
  }
  if (Cb){
    for (int j=0;j<2;j++){
      int n = n0 + wn + j*16 + l15;
      float bv = (bias && n < N) ? bias[n] : 0.f;
      for (int i=0;i<2;i++){
        int mbase = m0 + wm + i*16 + quad*4;
        for (int r=0;r<4;r++){
          float cv = acc[i][j][r] + bv;
          if (relu) cv = fmaxf(cv, 0.f);
          Cb[(size_t)(mbase+r)*Npad + n] = (n < N) ? f2b(cv) : (short)0;
        }
      }
    }
  } else {
    for (int j=0;j<2;j++){
      int n = n0 + wn + j*16 + l15;
      if (n >= N) continue;
      float bv = bias ? bias[n] : 0.f;
      for (int i=0;i<2;i++){
        int mbase = m0 + wm + i*16 + quad*4;
        for (int r=0;r<4;r++){
          float cv = acc[i][j][r] + bv;
          if (relu) cv = fmaxf(cv, 0.f);
          C[(size_t)(mbase+r)*N + n] = cv;
        }
      }
    }
  }
}

// ---- attention partial: block = (b,h,ksplit); 128 keys in LDS; 2 q/thread --
// No max-subtraction softmax -> disjoint-k partials (sum, o[8]) are additive.
__global__ __launch_bounds__(256) void t12_attn_part(
    const float* __restrict__ qkv, const int* __restrict__ toks,
    float* __restrict__ pp, float* __restrict__ ps){
  __shared__ float kb[KCH][8];
  __shared__ float vb[KCH][8];
  __shared__ float msk[KCH];
  int blk = blockIdx.x;
  int ks = blk & (NSPLIT-1);
  int bh = blk >> 2;
  int b = bh >> 3, h = bh & 7;
  int tid = threadIdx.x;
  int kbase = ks*KCH;
  {
    int r = tid >> 1, half = (tid & 1)*4;          // 256 threads cover 128 rows x2
    const float* src = qkv + (size_t)(b*SEQ + kbase + r)*192 + h*8 + half;
    *(float4*)&kb[r][half] = *(const float4*)(src + 64);
    *(float4*)&vb[r][half] = *(const float4*)(src + 128);
  }
  if (tid < KCH)
    msk[tid] = (toks[b*SEQ + kbase + tid]==0) ? -1e9f : 0.f;
  __syncthreads();
  const float scale = 0.057735026918962574f;  // 1/sqrt(300)
  float q0[8], q1[8];
  {
    const float* s0 = qkv + (size_t)(b*SEQ+tid)*192 + h*8;
    const float* s1 = qkv + (size_t)(b*SEQ+tid+256)*192 + h*8;
    *(float4*)&q0[0] = *(const float4*)s0; *(float4*)&q0[4] = *(const float4*)(s0+4);
    *(float4*)&q1[0] = *(const float4*)s1; *(float4*)&q1[4] = *(const float4*)(s1+4);
  }
  float sum0=0.f, sum1=0.f, o0[8]={}, o1[8]={};
  #pragma unroll 2
  for (int k=0; k<KCH; k++){
    float kr[8], vr[8];
    *(float4*)&kr[0] = *(float4*)&kb[k][0]; *(float4*)&kr[4] = *(float4*)&kb[k][4];
    *(float4*)&vr[0] = *(float4*)&vb[k][0]; *(float4*)&vr[4] = *(float4*)&vb[k][4];
    float s0v=0.f, s1v=0.f;
    for (int d=0; d<8; d++){ s0v = fmaf(q0[d],kr[d],s0v); s1v = fmaf(q1[d],kr[d],s1v); }
    float m = msk[k];
    float p0 = __expf(fminf(fmaf(s0v,scale,m), 60.f));   // masked: ~-1e9 -> exp = 0
    float p1 = __expf(fminf(fmaf(s1v,scale,m), 60.f));
    sum0 += p0; sum1 += p1;
    for (int d=0; d<8; d++){ o0[d] = fmaf(p0,vr[d],o0[d]); o1[d] = fmaf(p1,vr[d],o1[d]); }
  }
  size_t sbase = (size_t)ks*BSQ*64;
  float* d0 = pp + sbase + (size_t)(b*SEQ+tid)*64 + h*8;
  float* d1 = pp + sbase + (size_t)(b*SEQ+tid+256)*64 + h*8;
  *(float4*)d0 = *(float4*)&o0[0]; *(float4*)(d0+4) = *(float4*)&o0[4];
  *(float4*)d1 = *(float4*)&o1[0]; *(float4*)(d1+4) = *(float4*)&o1[4];
  size_t pbase = (size_t)ks*BSQ*8;
  ps[pbase + (size_t)(b*SEQ+tid)*8 + h] = sum0;
  ps[pbase + (size_t)(b*SEQ+tid+256)*8 + h] = sum1;
}

// ---- attention combine: sum NSPLIT partials, normalize, emit bf16 ----------
__global__ __launch_bounds__(256) void t12_attn_comb(
    const float* __restrict__ pp, const float* __restrict__ ps,
    short* __restrict__ aout){
  int idx = blockIdx.x*256 + threadIdx.x;   // (bsq, h)
  if (idx >= BSQ*8) return;
  float s = 0.f;
  for (int k=0;k<NSPLIT;k++) s += ps[(size_t)k*BSQ*8 + idx];
  float inv = 1.f/s;
  int bsq = idx >> 3, h = idx & 7;
  size_t base = (size_t)bsq*64 + h*8;
  float o[8] = {};
  for (int k=0;k<NSPLIT;k++){
    const float4* p = (const float4*)(pp + (size_t)k*BSQ*64 + base);
    float4 a = p[0], bq = p[1];
    o[0]+=a.x; o[1]+=a.y; o[2]+=a.z; o[3]+=a.w;
    o[4]+=bq.x; o[5]+=bq.y; o[6]+=bq.z; o[7]+=bq.w;
  }
  short8 r;
  for (int d=0;d<8;d++) r[d] = f2b(o[d]*inv);
  *(short8*)(aout + base) = r;
}

// ---- fused residual add + LayerNorm (ddof=1); optional bf16 copy + acc+= ---
__global__ __launch_bounds__(256) void t10_addnorm(
                 const float* __restrict__ xa, const float* __restrict__ xb,
                 float* __restrict__ y, short* __restrict__ ybf,
                 float* __restrict__ accum, short* __restrict__ accbf,
                 const float* __restrict__ gamma, const float* __restrict__ beta,
                 int l){
  __shared__ float red[8];
  int row = blockIdx.x, tid = threadIdx.x;
  size_t base = (size_t)row*HIDD;
  size_t bbase = (size_t)row*320;
  float v0 = xa[base+tid] + xb[base+tid];
  float v1 = 0.f;
  int has1 = (tid+256 < HIDD);
  if (has1) v1 = xa[base+tid+256] + xb[base+tid+256];
  float s = v0+v1, sq = v0*v0+v1*v1;
  for (int off=32; off; off>>=1){ s += __shfl_down(s,off); sq += __shfl_down(sq,off); }
  int lane = tid & 63, w = tid >> 6;
  if (lane==0){ red[w]=s; red[4+w]=sq; }
  __syncthreads();
  float sum = red[0]+red[1]+red[2]+red[3];
  float ssq = red[4]+red[5]+red[6]+red[7];
  float mu  = sum * (1.0f/HIDD);
  float var = (ssq - (float)HIDD*mu*mu) * (1.0f/(HIDD-1));
  float rstd = rsqrtf(var + 1e-8f);
  float g = gamma[l], be = beta[l];
  float o0 = g*(v0-mu)*rstd + be;
  y[base+tid] = o0;
  if (ybf) ybf[bbase+tid] = f2b(o0);
  if (accum){
    float a0 = accum[base+tid] + o0;
    accum[base+tid] = a0;
    if (accbf) accbf[bbase+tid] = f2b(a0);
  }
  if (has1){
    float o1 = g*(v1-mu)*rstd + be;
    y[base+tid+256] = o1;
    if (ybf) ybf[bbase+tid+256] = f2b(o1);
    if (accum){
      float a1 = accum[base+tid+256] + o1;
      accum[base+tid+256] = a1;
      if (accbf) accbf[bbase+tid+256] = f2b(a1);
    }
  } else if (tid+256 < 320){
    if (ybf) ybf[bbase+tid+256] = 0;
    if (accbf) accbf[bbase+tid+256] = 0;
  }
}

// ---------------- fp32 tiled GEMM (classifier only, M=32) -------------------
#define GBM 64
#define GBN 64
#define GBK 16
__global__ __launch_bounds__(256) void t9_gemm(
                 const float* __restrict__ A, const float* __restrict__ W,
                 const float* __restrict__ bias, float* __restrict__ C,
                 int M, int N, int K, int relu){
  __shared__ float sA[GBM][GBK+1];
  __shared__ float sW[GBK][GBN];
  int tid = threadIdx.x;
  int tx = tid & 15, ty = tid >> 4;
  int m0 = blockIdx.y * GBM, n0 = blockIdx.x * GBN;
  float cacc[4][4] = {};
  int lr = tid >> 4, lk = tid & 15;
  int lc = tid & 63, lkb = tid >> 6;
  for (int k0 = 0; k0 < K; k0 += GBK){
    for (int t = 0; t < 4; t++){
      int row = lr + t*16;
      float vv = 0.f;
      int gm = m0 + row, gk = k0 + lk;
      if (gm < M && gk < K) vv = A[(size_t)gm*K + gk];
      sA[row][lk] = vv;
    }
    for (int t = 0; t < 4; t++){
      int kk = lkb + t*4;
      float vv = 0.f;
      int gk = k0 + kk, gn = n0 + lc;
      if (gk < K && gn < N) vv = W[(size_t)gk*N + gn];
      sW[kk][lc] = vv;
    }
    __syncthreads();
    for (int kk = 0; kk < GBK; kk++){
      float a0[4], b0[4];
      for (int i=0;i<4;i++) a0[i] = sA[ty*4+i][kk];
      for (int j=0;j<4;j++) b0[j] = sW[kk][tx*4+j];
      for (int i=0;i<4;i++)
        for (int j=0;j<4;j++)
          cacc[i][j] = fmaf(a0[i], b0[j], cacc[i][j]);
    }
    __syncthreads();
  }
  for (int i=0;i<4;i++){
    int m = m0 + ty*4 + i;
    if (m >= M) continue;
    for (int j=0;j<4;j++){
      int n = n0 + tx*4 + j;
      if (n >= N) continue;
      float cv = cacc[i][j];
      if (bias) cv += bias[n];
      if (relu) cv = fmaxf(cv, 0.f);
      C[(size_t)m*N + n] = cv;
    }
  }
}

// ---------------- sum over sequence: (B,S,HID) -> (B,HID) -------------------
__global__ void t10_colsum(const float* __restrict__ outb, float* __restrict__ sums){
  int b = blockIdx.x, j = threadIdx.x;
  if (j >= HIDD) return;
  float s = 0.f;
  size_t base = (size_t)b*SEQ*HIDD;
  for (int t=0; t<SEQ; t++) s += outb[base + (size_t)t*HIDD + j];
  sums[b*HIDD + j] = s;
}

// ---------------- classifier head: LayerNorm(ddof=1) + softmax -> fp32 -----
__device__ __forceinline__ float t10_bsum(float val, float* red){
  for (int off=32; off; off>>=1) val += __shfl_down(val, off);
  __syncthreads();
  if ((threadIdx.x & 63)==0) red[threadIdx.x>>6] = val;
  __syncthreads();
  return red[0]+red[1]+red[2]+red[3];
}
__device__ __forceinline__ float t10_bmax(float val, float* red){
  for (int off=32; off; off>>=1) val = fmaxf(val, __shfl_down(val, off));
  __syncthreads();
  if ((threadIdx.x & 63)==0) red[threadIdx.x>>6] = val;
  __syncthreads();
  return fmaxf(fmaxf(red[0],red[1]), fmaxf(red[2],red[3]));
}

__global__ __launch_bounds__(256) void t10_final(
                  const float* __restrict__ logits,
                  const float* __restrict__ gf, const float* __restrict__ bff,
                  float* __restrict__ outp){
  __shared__ float red[4];
  int b = blockIdx.x, tid = threadIdx.x;
  size_t base = (size_t)b*NCLS;
  float v[4];
  float s = 0.f, sq = 0.f;
  for (int t=0;t<4;t++){
    int j = tid + t*256;
    float x = (j < NCLS) ? logits[base+j] : 0.f;
    v[t] = x; s += x; sq += x*x;
  }
  s  = t10_bsum(s, red);
  sq = t10_bsum(sq, red);
  float mu  = s * (1.0f/NCLS);
  float var = (sq - (float)NCLS*mu*mu) * (1.0f/(NCLS-1));
  float rstd = rsqrtf(var + 1e-8f);
  float g = gf[0], be = bff[0];
  float y[4]; float mx = -1e30f;
  for (int t=0;t<4;t++){
    int j = tid + t*256;
    y[t] = g*(v[t]-mu)*rstd + be;
    if (j < NCLS) mx = fmaxf(mx, y[t]);
  }
  mx = t10_bmax(mx, red);
  float p[4]; float es = 0.f;
  for (int t=0;t<4;t++){
    int j = tid + t*256;
    p[t] = (j < NCLS) ? __expf(y[t]-mx) : 0.f;
    es += p[t];
  }
  es = t10_bsum(es, red);
  float inv = 1.0f/es;
  for (int t=0;t<4;t++){
    int j = tid + t*256;
    if (j < NCLS) outp[base+j] = p[t]*inv;
  }
}

// ---------------------------------------------------------------------------
extern "C" void kernel_launch(void* const* d_in, const int* in_sizes, int n_in,
                              void* d_out, int out_size, void* d_ws, size_t ws_size,
                              hipStream_t stream){
  const int*   toks = (const int*)d_in[0];
  const float* emb  = (const float*)d_in[1];
  const float* WQ   = (const float*)d_in[2];
  const float* WK   = (const float*)d_in[3];
  const float* WV   = (const float*)d_in[4];
  const float* WO   = (const float*)d_in[5];
  const float* W1   = (const float*)d_in[6];
  const float* b1   = (const float*)d_in[7];
  const float* W2   = (const float*)d_in[8];
  const float* b2   = (const float*)d_in[9];
  const float* g1   = (const float*)d_in[10];
  const float* be1  = (const float*)d_in[11];
  const float* g2   = (const float*)d_in[12];
  const float* be2  = (const float*)d_in[13];
  const float* Vd   = (const float*)d_in[14];
  const float* gf   = (const float*)d_in[15];
  const float* bff  = (const float*)d_in[16];
  float* outp = (float*)d_out;

  // fp32 buffers
  float* acc    = (float*)d_ws;                         // [BSQ][300]
  float* xn     = acc    + (size_t)BSQ*HIDD;            // [BSQ][300]
  float* outb   = xn     + (size_t)BSQ*HIDD;            // [BSQ][300]
  float* tmp    = outb   + (size_t)BSQ*HIDD;            // [BSQ][300]
  float* qkv    = tmp    + (size_t)BSQ*HIDD;            // [BSQ][192]
  float* sums   = qkv    + (size_t)BSQ*192;             // [32][300]
  float* logits = sums   + BATCH*HIDD;                  // [32][1000]
  // attention partials alias tmp (dead during attention):
  // pp = NSPLIT*BSQ*64 floats (4.19M) + ps = NSPLIT*BSQ*8 (0.52M) <= BSQ*300 (4.92M)
  float* pp     = tmp;
  float* ps     = tmp + (size_t)NSPLIT*BSQ*64;
  // bf16 buffers
  short* acc_bf = (short*)(logits + BATCH*NCLS);        // [BSQ][320]
  short* xn_bf  = acc_bf + (size_t)BSQ*320;             // [BSQ][320]
  short* aat_bf = xn_bf  + (size_t)BSQ*320;             // [BSQ][64]
  short* ff1_bf = aat_bf + (size_t)BSQ*64;              // [BSQ][1216]
  // bf16 weights
  short* wqkv = ff1_bf + (size_t)BSQ*1216;              // [6][192][320]
  short* wo   = wqkv + (size_t)6*192*320;               // [6][320][64]
  short* w1t  = wo   + (size_t)6*320*64;                // [6][1216][320]
  short* w2t  = w1t  + (size_t)6*1216*320;              // [6][320][1216]

  {
    int tq = 6*64*320;
    prep_w<<<(tq+255)/256,256,0,stream>>>(WQ, wqkv, 300, 64, 320, 64, 0,   19200, 61440, tq, 1);
    prep_w<<<(tq+255)/256,256,0,stream>>>(WK, wqkv, 300, 64, 320, 64, 64,  19200, 61440, tq, 1);
    prep_w<<<(tq+255)/256,256,0,stream>>>(WV, wqkv, 300, 64, 320, 64, 128, 19200, 61440, tq, 1);
    int to = 6*320*64;
    prep_w<<<(to+255)/256,256,0,stream>>>(WO, wo, 64, 300, 64, 320, 0, 19200, 20480, to, 0);
    int t1 = 6*1216*320;
    prep_w<<<(t1+255)/256,256,0,stream>>>(W1, w1t, 300, 1200, 320, 1216, 0, 360000, 389120, t1, 0);
    int t2 = 6*320*1216;
    prep_w<<<(t2+255)/256,256,0,stream>>>(W2, w2t, 1200, 300, 1216, 320, 0, 360000, 389120, t2, 0);
  }

  t10_embed<<<(BSQ*320+255)/256, 256, 0, stream>>>(toks, emb, acc, acc_bf);

  for (int l = 0; l < NLAYERS; l++){
    // QKV: [BSQ][320]bf16 @ [192][320] -> qkv fp32 [BSQ][192]
    mm_a16<<<256*3,256,0,stream>>>(acc_bf, wqkv + (size_t)l*61440, nullptr, qkv, nullptr,
                                   BSQ, 192, 320, 0, 3, 0);
    t12_attn_part<<<BATCH*NHEAD*NSPLIT, 256, 0, stream>>>(qkv, toks, pp, ps);
    t12_attn_comb<<<(BSQ*8)/256, 256, 0, stream>>>(pp, ps, aat_bf);
    // WO: [BSQ][64]bf16 @ [320][64] -> tmp fp32 [BSQ][300]
    mm_a16<<<256*5,256,0,stream>>>(aat_bf, wo + (size_t)l*20480, nullptr, tmp, nullptr,
                                   BSQ, 300, 64, 0, 5, 0);
    t10_addnorm<<<BSQ,256,0,stream>>>(tmp, acc, xn, xn_bf, nullptr, nullptr, g1, be1, l);
    // FF1: [BSQ][320]bf16 @ [1216][320] -> ff1 bf16 [BSQ][1216] (bias+relu)
    mm_a16<<<256*19,256,0,stream>>>(xn_bf, w1t + (size_t)l*389120, b1 + (size_t)l*FFD,
                                    nullptr, ff1_bf, BSQ, 1200, 320, 1216, 19, 1);
    // FF2: [BSQ][1216]bf16 @ [320][1216] -> tmp fp32 [BSQ][300] (bias)
    mm_a16<<<256*5,256,0,stream>>>(ff1_bf, w2t + (size_t)l*389120, b2 + (size_t)l*HIDD,
                                   tmp, nullptr, BSQ, 300, 1216, 0, 5, 0);
    t10_addnorm<<<BSQ,256,0,stream>>>(tmp, xn, outb, nullptr, acc, acc_bf, g2, be2, l);
  }

  t10_colsum<<<BATCH, 320, 0, stream>>>(outb, sums);
  t9_gemm<<<dim3((NCLS+GBN-1)/GBN, 1),256,0,stream>>>(sums, Vd, nullptr, logits, BATCH, NCLS, HIDD, 0);
  t10_final<<<BATCH, 256, 0, stream>>>(logits, gf, bff, outp);

  hipStreamCaptureStatus cs = hipStreamCaptureStatusNone;
  hipStreamIsCapturing(stream, &cs);
  if (cs == hipStreamCaptureStatusNone){
    hipError_t e_sync = hipStreamSynchronize(stream);
    float ho[4] = {-1,-1,-1,-1};
    hipMemcpy(ho, d_out, 16, hipMemcpyDeviceToHost);
    fprintf(stderr, "[t12r] sync=%s out[0..3]=%g,%g,%g,%g\n",
            hipGetErrorString(e_sync), ho[0], ho[1], ho[2], ho[3]);
    fflush(stderr);
  }
}

// Round 4
// 1230.394 us; speedup vs baseline: 1.3809x; 1.0381x over previous
//
#include <hip/hip_runtime.h>
#include <hip/hip_bf16.h>
#include <cstdio>
#include <cstdint>

#define BATCH 32
#define SEQ 512
#define BSQ (BATCH*SEQ)      // 16384
#define HIDD 300
#define HD 64
#define NHEAD 8
#define DHEAD 8
#define NLAYERS 6
#define FFD 1200
#define NCLS 1000
#define NSPLIT 4
#define KCH (SEQ/NSPLIT)     // 128 keys per block
#define CLS_KS 4
#define CLS_KC (HIDD/CLS_KS) // 75

typedef short short8 __attribute__((ext_vector_type(8)));
typedef float floatx4 __attribute__((ext_vector_type(4)));

__device__ __forceinline__ short f2b(float v){
  __hip_bfloat16 h = __float2bfloat16(v);
  short s; __builtin_memcpy(&s, &h, 2); return s;
}

// ------- embedding + positional encoding -> acc = 2*emb + pos (fp32 + bf16) -
// grid covers BSQ*320: cols 300..319 zero-pad the bf16 copy only.
__global__ void t10_embed(const int* __restrict__ toks,
                          const float* __restrict__ emb,
                          float* __restrict__ acc,
                          short* __restrict__ accbf){
  int idx = blockIdx.x*256 + threadIdx.x;
  if (idx >= BSQ*320) return;
  int row = idx / 320;
  int j   = idx - row*320;
  if (j >= HIDD){ accbf[(size_t)row*320 + j] = 0; return; }
  int t = toks[row];
  float e = emb[(size_t)t*HIDD + j];
  int s = row & (SEQ-1);
  float expo = (float)(j & ~1) * (1.0f/(float)HIDD);
  float ang  = (float)s * expf(-expo * 9.210340371976184f);
  float pe   = (j & 1) ? cosf(ang) : sinf(ang);
  float v = 2.0f*e + pe;
  acc[(size_t)row*HIDD + j] = v;
  accbf[(size_t)row*320 + j] = f2b(v);
}

// ------- weight prep: fp32 [K][N] -> bf16 transposed [Npad][Kpad] -----------
// perm: dest col n takes source col (n&7)*8 + (n>>3)  (head-major reorder)
__global__ void prep_w(const float* __restrict__ src, short* __restrict__ dst,
                       int K, int N, int Kpad, int rows, int nbase,
                       int sls, int dls, int total, int perm){
  int idx = blockIdx.x*256 + threadIdx.x;
  if (idx >= total) return;
  int l   = idx / (rows*Kpad);
  int rem = idx - l*(rows*Kpad);
  int n = rem / Kpad;
  int k = rem - n*Kpad;
  int sc = perm ? ((n & 7)*8 + (n >> 3)) : n;
  float v = (n < N && k < K) ? src[(size_t)l*sls + (size_t)k*N + sc] : 0.f;
  dst[(size_t)l*dls + (size_t)(nbase+n)*Kpad + k] = f2b(v);
}

// ---- bf16 MFMA GEMM: C[M,N](f32) or Cb[M,Npad](bf16) = A[M,Kpad](bf16) @ Wt
// A is pre-converted, zero-padded bf16.  1-D grid with XCD-bijective swizzle:
// each XCD gets a contiguous chunk of m-tiles (n-fastest inside) so all
// n-blocks sharing an A-tile hit the same XCD L2.
__global__ __launch_bounds__(256) void mm_a16(
    const short* __restrict__ A, const short* __restrict__ Wt,
    const float* __restrict__ bias, float* __restrict__ C,
    short* __restrict__ Cb,
    int M, int N, int Kpad, int Npad, int nnb, int relu){
  __shared__ short sA[64][40];
  __shared__ short sB[64][40];
  int wg = blockIdx.x;
  int cpx = gridDim.x >> 3;                 // nwg is always a multiple of 8
  int swz = (wg & 7)*cpx + (wg >> 3);
  int mt = swz / nnb, nt = swz - mt*nnb;
  int m0 = mt*64, n0 = nt*64;
  int tid = threadIdx.x;
  int lane = tid & 63, wv = tid >> 6;
  int wm = (wv & 1)*32, wn = (wv >> 1)*32;
  int l15 = lane & 15, quad = lane >> 4;
  floatx4 acc[2][2] = {};
  int srow = tid >> 2, sko = (tid & 3)*8;
  const short* Arow = A  + (size_t)(m0 + srow)*Kpad + sko;
  const short* Brow = Wt + (size_t)(n0 + srow)*Kpad + sko;
  int nch = Kpad >> 5;
  for (int c = 0; c < nch; c++){
    int k0 = c*32;
    __syncthreads();
    *(short8*)&sA[srow][sko] = *(const short8*)(Arow + k0);
    *(short8*)&sB[srow][sko] = *(const short8*)(Brow + k0);
    __syncthreads();
    short8 af[2], bf[2];
    for (int i=0;i<2;i++)
      af[i] = *(const short8*)&sA[wm + i*16 + l15][quad*8];
    for (int j=0;j<2;j++)
      bf[j] = *(const short8*)&sB[wn + j*16 + l15][quad*8];
    for (int i=0;i<2;i++)
      for (int j=0;j<2;j++)
        acc[i][j] = __builtin_amdgcn_mfma_f32_16x16x32_bf16(af[i], bf[j], acc[i][j], 0,0,0);
  }
  if (Cb){
    for (int j=0;j<2;j++){
      int n = n0 + wn + j*16 + l15;
      float bv = (bias && n < N) ? bias[n] : 0.f;
      for (int i=0;i<2;i++){
        int mbase = m0 + wm + i*16 + quad*4;
        for (int r=0;r<4;r++){
          float cv = acc[i][j][r] + bv;
          if (relu) cv = fmaxf(cv, 0.f);
          Cb[(size_t)(mbase+r)*Npad + n] = (n < N) ? f2b(cv) : (short)0;
        }
      }
    }
  } else {
    for (int j=0;j<2;j++){
      int n = n0 + wn + j*16 + l15;
      if (n >= N) continue;
      float bv = bias ? bias[n] : 0.f;
      for (int i=0;i<2;i++){
        int mbase = m0 + wm + i*16 + quad*4;
        for (int r=0;r<4;r++){
          float cv = acc[i][j][r] + bv;
          if (relu) cv = fmaxf(cv, 0.f);
          C[(size_t)(mbase+r)*N + n] = cv;
        }
      }
    }
  }
}

// ---- attention partial: block = (b,h,ksplit); 128 keys in LDS; 2 q/thread --
// No max-subtraction softmax -> disjoint-k partials (sum, o[8]) are additive.
__global__ __launch_bounds__(256) void t12_attn_part(
    const float* __restrict__ qkv, const int* __restrict__ toks,
    float* __restrict__ pp, float* __restrict__ ps){
  __shared__ float kb[KCH][8];
  __shared__ float vb[KCH][8];
  __shared__ float msk[KCH];
  int blk = blockIdx.x;
  int ks = blk & (NSPLIT-1);
  int bh = blk >> 2;
  int b = bh >> 3, h = bh & 7;
  int tid = threadIdx.x;
  int kbase = ks*KCH;
  {
    int r = tid >> 1, half = (tid & 1)*4;          // 256 threads cover 128 rows x2
    const float* src = qkv + (size_t)(b*SEQ + kbase + r)*192 + h*8 + half;
    *(float4*)&kb[r][half] = *(const float4*)(src + 64);
    *(float4*)&vb[r][half] = *(const float4*)(src + 128);
  }
  if (tid < KCH)
    msk[tid] = (toks[b*SEQ + kbase + tid]==0) ? -1e9f : 0.f;
  __syncthreads();
  const float scale = 0.057735026918962574f;  // 1/sqrt(300)
  float q0[8], q1[8];
  {
    const float* s0 = qkv + (size_t)(b*SEQ+tid)*192 + h*8;
    const float* s1 = qkv + (size_t)(b*SEQ+tid+256)*192 + h*8;
    *(float4*)&q0[0] = *(const float4*)s0; *(float4*)&q0[4] = *(const float4*)(s0+4);
    *(float4*)&q1[0] = *(const float4*)s1; *(float4*)&q1[4] = *(const float4*)(s1+4);
  }
  float sum0=0.f, sum1=0.f, o0[8]={}, o1[8]={};
  #pragma unroll 2
  for (int k=0; k<KCH; k++){
    float kr[8], vr[8];
    *(float4*)&kr[0] = *(float4*)&kb[k][0]; *(float4*)&kr[4] = *(float4*)&kb[k][4];
    *(float4*)&vr[0] = *(float4*)&vb[k][0]; *(float4*)&vr[4] = *(float4*)&vb[k][4];
    float s0v=0.f, s1v=0.f;
    for (int d=0; d<8; d++){ s0v = fmaf(q0[d],kr[d],s0v); s1v = fmaf(q1[d],kr[d],s1v); }
    float m = msk[k];
    float p0 = __expf(fminf(fmaf(s0v,scale,m), 60.f));   // masked: ~-1e9 -> exp = 0
    float p1 = __expf(fminf(fmaf(s1v,scale,m), 60.f));
    sum0 += p0; sum1 += p1;
    for (int d=0; d<8; d++){ o0[d] = fmaf(p0,vr[d],o0[d]); o1[d] = fmaf(p1,vr[d],o1[d]); }
  }
  size_t sbase = (size_t)ks*BSQ*64;
  float* d0 = pp + sbase + (size_t)(b*SEQ+tid)*64 + h*8;
  float* d1 = pp + sbase + (size_t)(b*SEQ+tid+256)*64 + h*8;
  *(float4*)d0 = *(float4*)&o0[0]; *(float4*)(d0+4) = *(float4*)&o0[4];
  *(float4*)d1 = *(float4*)&o1[0]; *(float4*)(d1+4) = *(float4*)&o1[4];
  size_t pbase = (size_t)ks*BSQ*8;
  ps[pbase + (size_t)(b*SEQ+tid)*8 + h] = sum0;
  ps[pbase + (size_t)(b*SEQ+tid+256)*8 + h] = sum1;
}

// ---- attention combine: sum NSPLIT partials, normalize, emit bf16 ----------
__global__ __launch_bounds__(256) void t12_attn_comb(
    const float* __restrict__ pp, const float* __restrict__ ps,
    short* __restrict__ aout){
  int idx = blockIdx.x*256 + threadIdx.x;   // (bsq, h)
  if (idx >= BSQ*8) return;
  float s = 0.f;
  for (int k=0;k<NSPLIT;k++) s += ps[(size_t)k*BSQ*8 + idx];
  float inv = 1.f/s;
  int bsq = idx >> 3, h = idx & 7;
  size_t base = (size_t)bsq*64 + h*8;
  float o[8] = {};
  for (int k=0;k<NSPLIT;k++){
    const float4* p = (const float4*)(pp + (size_t)k*BSQ*64 + base);
    float4 a = p[0], bq = p[1];
    o[0]+=a.x; o[1]+=a.y; o[2]+=a.z; o[3]+=a.w;
    o[4]+=bq.x; o[5]+=bq.y; o[6]+=bq.z; o[7]+=bq.w;
  }
  short8 r;
  for (int d=0;d<8;d++) r[d] = f2b(o[d]*inv);
  *(short8*)(aout + base) = r;
}

// ---- fused residual add + LayerNorm (ddof=1); optional bf16 copy + acc+= ---
__global__ __launch_bounds__(256) void t10_addnorm(
                 const float* __restrict__ xa, const float* __restrict__ xb,
                 float* __restrict__ y, short* __restrict__ ybf,
                 float* __restrict__ accum, short* __restrict__ accbf,
                 const float* __restrict__ gamma, const float* __restrict__ beta,
                 int l){
  __shared__ float red[8];
  int row = blockIdx.x, tid = threadIdx.x;
  size_t base = (size_t)row*HIDD;
  size_t bbase = (size_t)row*320;
  float v0 = xa[base+tid] + xb[base+tid];
  float v1 = 0.f;
  int has1 = (tid+256 < HIDD);
  if (has1) v1 = xa[base+tid+256] + xb[base+tid+256];
  float s = v0+v1, sq = v0*v0+v1*v1;
  for (int off=32; off; off>>=1){ s += __shfl_down(s,off); sq += __shfl_down(sq,off); }
  int lane = tid & 63, w = tid >> 6;
  if (lane==0){ red[w]=s; red[4+w]=sq; }
  __syncthreads();
  float sum = red[0]+red[1]+red[2]+red[3];
  float ssq = red[4]+red[5]+red[6]+red[7];
  float mu  = sum * (1.0f/HIDD);
  float var = (ssq - (float)HIDD*mu*mu) * (1.0f/(HIDD-1));
  float rstd = rsqrtf(var + 1e-8f);
  float g = gamma[l], be = beta[l];
  float o0 = g*(v0-mu)*rstd + be;
  y[base+tid] = o0;
  if (ybf) ybf[bbase+tid] = f2b(o0);
  if (accum){
    float a0 = accum[base+tid] + o0;
    accum[base+tid] = a0;
    if (accbf) accbf[bbase+tid] = f2b(a0);
  }
  if (has1){
    float o1 = g*(v1-mu)*rstd + be;
    y[base+tid+256] = o1;
    if (ybf) ybf[bbase+tid+256] = f2b(o1);
    if (accum){
      float a1 = accum[base+tid+256] + o1;
      accum[base+tid+256] = a1;
      if (accbf) accbf[bbase+tid+256] = f2b(a1);
    }
  } else if (tid+256 < 320){
    if (ybf) ybf[bbase+tid+256] = 0;
    if (accbf) accbf[bbase+tid+256] = 0;
  }
}

// ---- colsum stage 1: block = (b, seq-chunk of 64); sum 64 rows ------------
__global__ __launch_bounds__(256) void t13_colsum_part(
    const float* __restrict__ outb, float* __restrict__ part){
  int blk = blockIdx.x;            // 256 blocks: b*8 + c
  int b = blk >> 3, c = blk & 7;
  int tid = threadIdx.x;
  size_t base = (size_t)b*SEQ*HIDD + (size_t)c*64*HIDD;
  int j1 = tid + 256;
  float s0 = 0.f, s1 = 0.f;
  for (int t = 0; t < 64; t++){
    const float* row = outb + base + (size_t)t*HIDD;
    s0 += row[tid];
    if (j1 < HIDD) s1 += row[j1];
  }
  float* dst = part + (size_t)(c*BATCH + b)*HIDD;
  dst[tid] = s0;
  if (j1 < HIDD) dst[j1] = s1;
}

// ---- colsum stage 2: fold 8 partials -> sums[32][300] ----------------------
__global__ void t13_colsum_comb(const float* __restrict__ part,
                                float* __restrict__ sums){
  int idx = blockIdx.x*256 + threadIdx.x;   // b*300 + j
  if (idx >= BATCH*HIDD) return;
  float s = 0.f;
  for (int c = 0; c < 8; c++) s += part[(size_t)c*BATCH*HIDD + idx];
  sums[idx] = s;
}

// ---- classifier GEMM, split-K=4: thread = (kslice, m, n); 500 blocks -------
// sums[m][k] is wave-uniform broadcast; Vd[k][n] coalesced across lanes.
__global__ __launch_bounds__(256) void t13_cls(
    const float* __restrict__ sums, const float* __restrict__ W,
    float* __restrict__ plog){
  int gid = blockIdx.x*256 + threadIdx.x;
  if (gid >= CLS_KS*BATCH*NCLS) return;
  int c = gid / (BATCH*NCLS);
  int rem = gid - c*(BATCH*NCLS);
  int m = rem / NCLS, n = rem - m*NCLS;
  const float* arow = sums + m*HIDD + c*CLS_KC;
  const float* wcol = W + (size_t)c*CLS_KC*NCLS + n;
  float acc = 0.f;
  #pragma unroll 5
  for (int k = 0; k < CLS_KC; k++)
    acc = fmaf(arow[k], wcol[(size_t)k*NCLS], acc);
  plog[gid] = acc;
}

// ---------------- classifier head: LayerNorm(ddof=1) + softmax -> fp32 -----
__device__ __forceinline__ float t10_bsum(float val, float* red){
  for (int off=32; off; off>>=1) val += __shfl_down(val, off);
  __syncthreads();
  if ((threadIdx.x & 63)==0) red[threadIdx.x>>6] = val;
  __syncthreads();
  return red[0]+red[1]+red[2]+red[3];
}
__device__ __forceinline__ float t10_bmax(float val, float* red){
  for (int off=32; off; off>>=1) val = fmaxf(val, __shfl_down(val, off));
  __syncthreads();
  if ((threadIdx.x & 63)==0) red[threadIdx.x>>6] = val;
  __syncthreads();
  return fmaxf(fmaxf(red[0],red[1]), fmaxf(red[2],red[3]));
}

__global__ __launch_bounds__(256) void t10_final(
                  const float* __restrict__ plog,
                  const float* __restrict__ gf, const float* __restrict__ bff,
                  float* __restrict__ outp){
  __shared__ float red[4];
  int b = blockIdx.x, tid = threadIdx.x;
  size_t base = (size_t)b*NCLS;
  float v[4];
  float s = 0.f, sq = 0.f;
  for (int t=0;t<4;t++){
    int j = tid + t*256;
    float x = 0.f;
    if (j < NCLS){
      for (int c=0;c<CLS_KS;c++) x += plog[(size_t)c*BATCH*NCLS + base + j];
    }
    v[t] = x; s += x; sq += x*x;
  }
  s  = t10_bsum(s, red);
  sq = t10_bsum(sq, red);
  float mu  = s * (1.0f/NCLS);
  float var = (sq - (float)NCLS*mu*mu) * (1.0f/(NCLS-1));
  float rstd = rsqrtf(var + 1e-8f);
  float g = gf[0], be = bff[0];
  float y[4]; float mx = -1e30f;
  for (int t=0;t<4;t++){
    int j = tid + t*256;
    y[t] = g*(v[t]-mu)*rstd + be;
    if (j < NCLS) mx = fmaxf(mx, y[t]);
  }
  mx = t10_bmax(mx, red);
  float p[4]; float es = 0.f;
  for (int t=0;t<4;t++){
    int j = tid + t*256;
    p[t] = (j < NCLS) ? __expf(y[t]-mx) : 0.f;
    es += p[t];
  }
  es = t10_bsum(es, red);
  float inv = 1.0f/es;
  for (int t=0;t<4;t++){
    int j = tid + t*256;
    if (j < NCLS) outp[base+j] = p[t]*inv;
  }
}

// ---------------------------------------------------------------------------
extern "C" void kernel_launch(void* const* d_in, const int* in_sizes, int n_in,
                              void* d_out, int out_size, void* d_ws, size_t ws_size,
                              hipStream_t stream){
  const int*   toks = (const int*)d_in[0];
  const float* emb  = (const float*)d_in[1];
  const float* WQ   = (const float*)d_in[2];
  const float* WK   = (const float*)d_in[3];
  const float* WV   = (const float*)d_in[4];
  const float* WO   = (const float*)d_in[5];
  const float* W1   = (const float*)d_in[6];
  const float* b1   = (const float*)d_in[7];
  const float* W2   = (const float*)d_in[8];
  const float* b2   = (const float*)d_in[9];
  const float* g1   = (const float*)d_in[10];
  const float* be1  = (const float*)d_in[11];
  const float* g2   = (const float*)d_in[12];
  const float* be2  = (const float*)d_in[13];
  const float* Vd   = (const float*)d_in[14];
  const float* gf   = (const float*)d_in[15];
  const float* bff  = (const float*)d_in[16];
  float* outp = (float*)d_out;

  // fp32 buffers
  float* acc    = (float*)d_ws;                         // [BSQ][300]
  float* xn     = acc    + (size_t)BSQ*HIDD;            // [BSQ][300]
  float* outb   = xn     + (size_t)BSQ*HIDD;            // [BSQ][300]
  float* tmp    = outb   + (size_t)BSQ*HIDD;            // [BSQ][300]
  float* qkv    = tmp    + (size_t)BSQ*HIDD;            // [BSQ][192]
  float* sums   = qkv    + (size_t)BSQ*192;             // [32][300]
  float* logits = sums   + BATCH*HIDD;                  // [32][1000] (unused now)
  // attention partials alias tmp (dead during attention):
  // pp = NSPLIT*BSQ*64 floats (4.19M) + ps = NSPLIT*BSQ*8 (0.52M) <= BSQ*300 (4.92M)
  float* pp     = tmp;
  float* ps     = tmp + (size_t)NSPLIT*BSQ*64;
  // bf16 buffers
  short* acc_bf = (short*)(logits + BATCH*NCLS);        // [BSQ][320]
  short* xn_bf  = acc_bf + (size_t)BSQ*320;             // [BSQ][320]
  short* aat_bf = xn_bf  + (size_t)BSQ*320;             // [BSQ][64]
  short* ff1_bf = aat_bf + (size_t)BSQ*64;              // [BSQ][1216]
  // bf16 weights
  short* wqkv = ff1_bf + (size_t)BSQ*1216;              // [6][192][320]
  short* wo   = wqkv + (size_t)6*192*320;               // [6][320][64]
  short* w1t  = wo   + (size_t)6*320*64;                // [6][1216][320]
  short* w2t  = w1t  + (size_t)6*1216*320;              // [6][320][1216]
  // classifier-tail fp32 buffers (after weights; weight region is 4B-aligned)
  float* cspart = (float*)(w2t + (size_t)6*320*1216);   // [8][32][300]
  float* plog   = cspart + (size_t)8*BATCH*HIDD;        // [4][32][1000]

  {
    int tq = 6*64*320;
    prep_w<<<(tq+255)/256,256,0,stream>>>(WQ, wqkv, 300, 64, 320, 64, 0,   19200, 61440, tq, 1);
    prep_w<<<(tq+255)/256,256,0,stream>>>(WK, wqkv, 300, 64, 320, 64, 64,  19200, 61440, tq, 1);
    prep_w<<<(tq+255)/256,256,0,stream>>>(WV, wqkv, 300, 64, 320, 64, 128, 19200, 61440, tq, 1);
    int to = 6*320*64;
    prep_w<<<(to+255)/256,256,0,stream>>>(WO, wo, 64, 300, 64, 320, 0, 19200, 20480, to, 0);
    int t1 = 6*1216*320;
    prep_w<<<(t1+255)/256,256,0,stream>>>(W1, w1t, 300, 1200, 320, 1216, 0, 360000, 389120, t1, 0);
    int t2 = 6*320*1216;
    prep_w<<<(t2+255)/256,256,0,stream>>>(W2, w2t, 1200, 300, 1216, 320, 0, 360000, 389120, t2, 0);
  }

  t10_embed<<<(BSQ*320+255)/256, 256, 0, stream>>>(toks, emb, acc, acc_bf);

  for (int l = 0; l < NLAYERS; l++){
    // QKV: [BSQ][320]bf16 @ [192][320] -> qkv fp32 [BSQ][192]
    mm_a16<<<256*3,256,0,stream>>>(acc_bf, wqkv + (size_t)l*61440, nullptr, qkv, nullptr,
                                   BSQ, 192, 320, 0, 3, 0);
    t12_attn_part<<<BATCH*NHEAD*NSPLIT, 256, 0, stream>>>(qkv, toks, pp, ps);
    t12_attn_comb<<<(BSQ*8)/256, 256, 0, stream>>>(pp, ps, aat_bf);
    // WO: [BSQ][64]bf16 @ [320][64] -> tmp fp32 [BSQ][300]
    mm_a16<<<256*5,256,0,stream>>>(aat_bf, wo + (size_t)l*20480, nullptr, tmp, nullptr,
                                   BSQ, 300, 64, 0, 5, 0);
    t10_addnorm<<<BSQ,256,0,stream>>>(tmp, acc, xn, xn_bf, nullptr, nullptr, g1, be1, l);
    // FF1: [BSQ][320]bf16 @ [1216][320] -> ff1 bf16 [BSQ][1216] (bias+relu)
    mm_a16<<<256*19,256,0,stream>>>(xn_bf, w1t + (size_t)l*389120, b1 + (size_t)l*FFD,
                                    nullptr, ff1_bf, BSQ, 1200, 320, 1216, 19, 1);
    // FF2: [BSQ][1216]bf16 @ [320][1216] -> tmp fp32 [BSQ][300] (bias)
    mm_a16<<<256*5,256,0,stream>>>(ff1_bf, w2t + (size_t)l*389120, b2 + (size_t)l*HIDD,
                                   tmp, nullptr, BSQ, 300, 1216, 0, 5, 0);
    t10_addnorm<<<BSQ,256,0,stream>>>(tmp, xn, outb, nullptr, acc, acc_bf, g2, be2, l);
  }

  t13_colsum_part<<<BATCH*8, 256, 0, stream>>>(outb, cspart);
  t13_colsum_comb<<<(BATCH*HIDD+255)/256, 256, 0, stream>>>(cspart, sums);
  t13_cls<<<(CLS_KS*BATCH*NCLS)/256, 256, 0, stream>>>(sums, Vd, plog);
  t10_final<<<BATCH, 256, 0, stream>>>(plog, gf, bff, outp);

  hipStreamCaptureStatus cs = hipStreamCaptureStatusNone;
  hipStreamIsCapturing(stream, &cs);
  if (cs == hipStreamCaptureStatusNone){
    hipError_t e_sync = hipStreamSynchronize(stream);
    float ho[4] = {-1,-1,-1,-1};
    hipMemcpy(ho, d_out, 16, hipMemcpyDeviceToHost);
    fprintf(stderr, "[t13] sync=%s out[0..3]=%g,%g,%g,%g\n",
            hipGetErrorString(e_sync), ho[0], ho[1], ho[2], ho[3]);
    fflush(stderr);
  }
}

// Round 5
// 1127.146 us; speedup vs baseline: 1.5074x; 1.0916x over previous
//
#include <hip/hip_runtime.h>
#include <hip/hip_bf16.h>
#include <cstdio>
#include <cstdint>

#define BATCH 32
#define SEQ 512
#define BSQ (BATCH*SEQ)      // 16384
#define HIDD 300
#define HD 64
#define NHEAD 8
#define DHEAD 8
#define NLAYERS 6
#define FFD 1200
#define NCLS 1000
#define NSPLIT 4
#define KCH (SEQ/NSPLIT)     // 128 keys per block
#define CLS_KS 4
#define CLS_KC (HIDD/CLS_KS) // 75

typedef short short8 __attribute__((ext_vector_type(8)));
typedef float floatx4 __attribute__((ext_vector_type(4)));

__device__ __forceinline__ short f2b(float v){
  __hip_bfloat16 h = __float2bfloat16(v);
  short s; __builtin_memcpy(&s, &h, 2); return s;
}
__device__ __forceinline__ unsigned pk2(float a, float b){
  return (unsigned)(unsigned short)f2b(a) | ((unsigned)(unsigned short)f2b(b) << 16);
}

// ------- embedding + positional encoding -> acc = 2*emb + pos (fp32 + bf16) -
__global__ void t10_embed(const int* __restrict__ toks,
                          const float* __restrict__ emb,
                          float* __restrict__ acc,
                          short* __restrict__ accbf){
  int idx = blockIdx.x*256 + threadIdx.x;
  if (idx >= BSQ*320) return;
  int row = idx / 320;
  int j   = idx - row*320;
  if (j >= HIDD){ accbf[(size_t)row*320 + j] = 0; return; }
  int t = toks[row];
  float e = emb[(size_t)t*HIDD + j];
  int s = row & (SEQ-1);
  float expo = (float)(j & ~1) * (1.0f/(float)HIDD);
  float ang  = (float)s * expf(-expo * 9.210340371976184f);
  float pe   = (j & 1) ? cosf(ang) : sinf(ang);
  float v = 2.0f*e + pe;
  acc[(size_t)row*HIDD + j] = v;
  accbf[(size_t)row*320 + j] = f2b(v);
}

// ------- weight prep: fp32 [K][N] -> bf16 transposed [Npad][Kpad] -----------
__global__ void prep_w(const float* __restrict__ src, short* __restrict__ dst,
                       int K, int N, int Kpad, int rows, int nbase,
                       int sls, int dls, int total, int perm){
  int idx = blockIdx.x*256 + threadIdx.x;
  if (idx >= total) return;
  int l   = idx / (rows*Kpad);
  int rem = idx - l*(rows*Kpad);
  int n = rem / Kpad;
  int k = rem - n*Kpad;
  int sc = perm ? ((n & 7)*8 + (n >> 3)) : n;
  float v = (n < N && k < K) ? src[(size_t)l*sls + (size_t)k*N + sc] : 0.f;
  dst[(size_t)l*dls + (size_t)(nbase+n)*Kpad + k] = f2b(v);
}

// ---- bf16 MFMA GEMM (unchanged from round 4) -------------------------------
__global__ __launch_bounds__(256) void mm_a16(
    const short* __restrict__ A, const short* __restrict__ Wt,
    const float* __restrict__ bias, float* __restrict__ C,
    short* __restrict__ Cb,
    int M, int N, int Kpad, int Npad, int nnb, int relu){
  __shared__ short sA[64][40];
  __shared__ short sB[64][40];
  int wg = blockIdx.x;
  int cpx = gridDim.x >> 3;
  int swz = (wg & 7)*cpx + (wg >> 3);
  int mt = swz / nnb, nt = swz - mt*nnb;
  int m0 = mt*64, n0 = nt*64;
  int tid = threadIdx.x;
  int lane = tid & 63, wv = tid >> 6;
  int wm = (wv & 1)*32, wn = (wv >> 1)*32;
  int l15 = lane & 15, quad = lane >> 4;
  floatx4 acc[2][2] = {};
  int srow = tid >> 2, sko = (tid & 3)*8;
  const short* Arow = A  + (size_t)(m0 + srow)*Kpad + sko;
  const short* Brow = Wt + (size_t)(n0 + srow)*Kpad + sko;
  int nch = Kpad >> 5;
  for (int c = 0; c < nch; c++){
    int k0 = c*32;
    __syncthreads();
    *(short8*)&sA[srow][sko] = *(const short8*)(Arow + k0);
    *(short8*)&sB[srow][sko] = *(const short8*)(Brow + k0);
    __syncthreads();
    short8 af[2], bf[2];
    for (int i=0;i<2;i++)
      af[i] = *(const short8*)&sA[wm + i*16 + l15][quad*8];
    for (int j=0;j<2;j++)
      bf[j] = *(const short8*)&sB[wn + j*16 + l15][quad*8];
    for (int i=0;i<2;i++)
      for (int j=0;j<2;j++)
        acc[i][j] = __builtin_amdgcn_mfma_f32_16x16x32_bf16(af[i], bf[j], acc[i][j], 0,0,0);
  }
  if (Cb){
    for (int j=0;j<2;j++){
      int n = n0 + wn + j*16 + l15;
      float bv = (bias && n < N) ? bias[n] : 0.f;
      for (int i=0;i<2;i++){
        int mbase = m0 + wm + i*16 + quad*4;
        for (int r=0;r<4;r++){
          float cv = acc[i][j][r] + bv;
          if (relu) cv = fmaxf(cv, 0.f);
          Cb[(size_t)(mbase+r)*Npad + n] = (n < N) ? f2b(cv) : (short)0;
        }
      }
    }
  } else {
    for (int j=0;j<2;j++){
      int n = n0 + wn + j*16 + l15;
      if (n >= N) continue;
      float bv = bias ? bias[n] : 0.f;
      for (int i=0;i<2;i++){
        int mbase = m0 + wm + i*16 + quad*4;
        for (int r=0;r<4;r++){
          float cv = acc[i][j][r] + bv;
          if (relu) cv = fmaxf(cv, 0.f);
          C[(size_t)(mbase+r)*N + n] = cv;
        }
      }
    }
  }
}

// ---- MFMA attention partial: block = (b,h,ksplit); 128 keys ----------------
// QK^T swapped (A=K, B=Q): C col=q(lane&15), row=k(quad*4+r).  d=8 zero-padded
// to K=32.  P packed bf16 into per-wave LDS tile, PV via MFMA with V^T-frags
// in registers; V^T col d=8 is a ones-column producing sum(p) for free.
__global__ __launch_bounds__(256) void t14_attn(
    const float* __restrict__ qkv, const int* __restrict__ toks,
    float* __restrict__ pp, float* __restrict__ ps){
  __shared__ float kb[KCH][9];      // fp32 K rows, pad 9 -> conflict-free
  __shared__ float vb[KCH][9];
  __shared__ float msk[KCH];
  __shared__ short Pl[4][16][136];  // per-wave P tile bf16 [q][k], 272B rows
  int blk = blockIdx.x;
  int ks = blk & (NSPLIT-1);
  int bh = blk >> 2;
  int b = bh >> 3, h = bh & 7;
  int tid = threadIdx.x;
  int lane = tid & 63, w = tid >> 6;
  int quad = lane >> 4, l15 = lane & 15;
  int kbase = ks*KCH;
  // stage K,V fp32 coalesced: thread -> (row=tid>>1, half=(tid&1)*4)
  {
    int r = tid >> 1, half = (tid & 1)*4;
    const float* src = qkv + (size_t)(b*SEQ + kbase + r)*192 + h*8 + half;
    float4 kx = *(const float4*)(src + 64);
    float4 vx = *(const float4*)(src + 128);
    kb[r][half+0]=kx.x; kb[r][half+1]=kx.y; kb[r][half+2]=kx.z; kb[r][half+3]=kx.w;
    vb[r][half+0]=vx.x; vb[r][half+1]=vx.y; vb[r][half+2]=vx.z; vb[r][half+3]=vx.w;
  }
  if (tid < KCH)
    msk[tid] = (toks[b*SEQ + kbase + tid]==0) ? -1e9f : 0.f;
  __syncthreads();

  // K A-frags (8 k-tiles), reg-resident: lane row=l15, elems d=quad*8+j (0 for d>=8)
  short8 kfrag[8];
  #pragma unroll
  for (int kt=0;kt<8;kt++){
    short8 f; 
    #pragma unroll
    for (int j=0;j<8;j++) f[j] = 0;
    if (quad == 0){
      #pragma unroll
      for (int j=0;j<8;j++) f[j] = f2b(kb[kt*16 + l15][j]);
    }
    kfrag[kt] = f;
  }
  // V^T B-frags (4 k-slices): lane col d=l15, elems k=ks2*32+quad*8+j
  short8 vfrag[4];
  #pragma unroll
  for (int ks2=0;ks2<4;ks2++){
    short8 f;
    #pragma unroll
    for (int j=0;j<8;j++) f[j] = 0;
    if (l15 < 8){
      #pragma unroll
      for (int j=0;j<8;j++) f[j] = f2b(vb[ks2*32 + quad*8 + j][l15]);
    } else if (l15 == 8){
      #pragma unroll
      for (int j=0;j<8;j++) f[j] = (short)0x3F80;  // bf16 1.0 -> sum(p) column
    }
    vfrag[ks2] = f;
  }
  // per-lane mask values for the 4 k-rows per k-tile (broadcast reads)
  const float scale = 0.057735026918962574f;  // 1/sqrt(300), folded into Q

  for (int t = 0; t < 8; t++){
    int q0 = w*128 + t*16;
    // Q B-frag direct from global: lane col q=l15, elems d=quad*8+j
    short8 qf;
    #pragma unroll
    for (int j=0;j<8;j++) qf[j] = 0;
    if (quad == 0){
      const float* qsrc = qkv + (size_t)(b*SEQ + q0 + l15)*192 + h*8;
      float4 a = *(const float4*)qsrc;
      float4 c = *(const float4*)(qsrc + 4);
      qf[0]=f2b(a.x*scale); qf[1]=f2b(a.y*scale); qf[2]=f2b(a.z*scale); qf[3]=f2b(a.w*scale);
      qf[4]=f2b(c.x*scale); qf[5]=f2b(c.y*scale); qf[6]=f2b(c.z*scale); qf[7]=f2b(c.w*scale);
    }
    // QK^T + exp, two k-tiles at a time; pack p -> P_lds
    #pragma unroll
    for (int kt2 = 0; kt2 < 4; kt2++){
      floatx4 z = {0.f,0.f,0.f,0.f};
      floatx4 a0 = __builtin_amdgcn_mfma_f32_16x16x32_bf16(kfrag[2*kt2],   qf, z, 0,0,0);
      floatx4 a1 = __builtin_amdgcn_mfma_f32_16x16x32_bf16(kfrag[2*kt2+1], qf, z, 0,0,0);
      float p0[4], p1[4];
      #pragma unroll
      for (int r=0;r<4;r++){
        float m0 = msk[(2*kt2)*16   + quad*4 + r];
        float m1 = msk[(2*kt2+1)*16 + quad*4 + r];
        p0[r] = __expf(fminf(a0[r] + m0, 60.f));
        p1[r] = __expf(fminf(a1[r] + m1, 60.f));
      }
      uint2 u0, u1;
      u0.x = pk2(p0[0], p0[1]); u0.y = pk2(p0[2], p0[3]);
      u1.x = pk2(p1[0], p1[1]); u1.y = pk2(p1[2], p1[3]);
      *(uint2*)&Pl[w][l15][(2*kt2)*16   + quad*4] = u0;
      *(uint2*)&Pl[w][l15][(2*kt2+1)*16 + quad*4] = u1;
    }
    // PV: A=P (row=q=l15, elems k), B=V^T-frags; accumulate over 4 k-slices.
    // Pl[w] is wave-private; DS ops are wave-ordered -> no barrier needed.
    floatx4 o = {0.f,0.f,0.f,0.f};
    #pragma unroll
    for (int ks2=0; ks2<4; ks2++){
      short8 pa = *(const short8*)&Pl[w][l15][ks2*32 + quad*8];
      o = __builtin_amdgcn_mfma_f32_16x16x32_bf16(pa, vfrag[ks2], o, 0,0,0);
    }
    // C: col=l15 -> d (8 = sum), row=quad*4+r -> q
    if (l15 < 8){
      #pragma unroll
      for (int r=0;r<4;r++){
        int q = q0 + quad*4 + r;
        pp[(size_t)ks*BSQ*64 + (size_t)(b*SEQ+q)*64 + h*8 + l15] = o[r];
      }
    } else if (l15 == 8){
      #pragma unroll
      for (int r=0;r<4;r++){
        int q = q0 + quad*4 + r;
        ps[(size_t)ks*BSQ*8 + (size_t)(b*SEQ+q)*8 + h] = o[r];
      }
    }
  }
}

// ---- attention combine: sum NSPLIT partials, normalize, emit bf16 ----------
__global__ __launch_bounds__(256) void t12_attn_comb(
    const float* __restrict__ pp, const float* __restrict__ ps,
    short* __restrict__ aout){
  int idx = blockIdx.x*256 + threadIdx.x;   // (bsq, h)
  if (idx >= BSQ*8) return;
  float s = 0.f;
  for (int k=0;k<NSPLIT;k++) s += ps[(size_t)k*BSQ*8 + idx];
  float inv = 1.f/s;
  int bsq = idx >> 3, h = idx & 7;
  size_t base = (size_t)bsq*64 + h*8;
  float o[8] = {};
  for (int k=0;k<NSPLIT;k++){
    const float4* p = (const float4*)(pp + (size_t)k*BSQ*64 + base);
    float4 a = p[0], bq = p[1];
    o[0]+=a.x; o[1]+=a.y; o[2]+=a.z; o[3]+=a.w;
    o[4]+=bq.x; o[5]+=bq.y; o[6]+=bq.z; o[7]+=bq.w;
  }
  short8 r;
  for (int d=0;d<8;d++) r[d] = f2b(o[d]*inv);
  *(short8*)(aout + base) = r;
}

// ---- fused residual add + LayerNorm (ddof=1); optional bf16 copy + acc+= ---
__global__ __launch_bounds__(256) void t10_addnorm(
                 const float* __restrict__ xa, const float* __restrict__ xb,
                 float* __restrict__ y, short* __restrict__ ybf,
                 float* __restrict__ accum, short* __restrict__ accbf,
                 const float* __restrict__ gamma, const float* __restrict__ beta,
                 int l){
  __shared__ float red[8];
  int row = blockIdx.x, tid = threadIdx.x;
  size_t base = (size_t)row*HIDD;
  size_t bbase = (size_t)row*320;
  float v0 = xa[base+tid] + xb[base+tid];
  float v1 = 0.f;
  int has1 = (tid+256 < HIDD);
  if (has1) v1 = xa[base+tid+256] + xb[base+tid+256];
  float s = v0+v1, sq = v0*v0+v1*v1;
  for (int off=32; off; off>>=1){ s += __shfl_down(s,off); sq += __shfl_down(sq,off); }
  int lane = tid & 63, w = tid >> 6;
  if (lane==0){ red[w]=s; red[4+w]=sq; }
  __syncthreads();
  float sum = red[0]+red[1]+red[2]+red[3];
  float ssq = red[4]+red[5]+red[6]+red[7];
  float mu  = sum * (1.0f/HIDD);
  float var = (ssq - (float)HIDD*mu*mu) * (1.0f/(HIDD-1));
  float rstd = rsqrtf(var + 1e-8f);
  float g = gamma[l], be = beta[l];
  float o0 = g*(v0-mu)*rstd + be;
  y[base+tid] = o0;
  if (ybf) ybf[bbase+tid] = f2b(o0);
  if (accum){
    float a0 = accum[base+tid] + o0;
    accum[base+tid] = a0;
    if (accbf) accbf[bbase+tid] = f2b(a0);
  }
  if (has1){
    float o1 = g*(v1-mu)*rstd + be;
    y[base+tid+256] = o1;
    if (ybf) ybf[bbase+tid+256] = f2b(o1);
    if (accum){
      float a1 = accum[base+tid+256] + o1;
      accum[base+tid+256] = a1;
      if (accbf) accbf[bbase+tid+256] = f2b(a1);
    }
  } else if (tid+256 < 320){
    if (ybf) ybf[bbase+tid+256] = 0;
    if (accbf) accbf[bbase+tid+256] = 0;
  }
}

// ---- colsum stage 1: block = (b, seq-chunk of 64); sum 64 rows ------------
__global__ __launch_bounds__(256) void t13_colsum_part(
    const float* __restrict__ outb, float* __restrict__ part){
  int blk = blockIdx.x;            // 256 blocks: b*8 + c
  int b = blk >> 3, c = blk & 7;
  int tid = threadIdx.x;
  size_t base = (size_t)b*SEQ*HIDD + (size_t)c*64*HIDD;
  int j1 = tid + 256;
  float s0 = 0.f, s1 = 0.f;
  for (int t = 0; t < 64; t++){
    const float* row = outb + base + (size_t)t*HIDD;
    s0 += row[tid];
    if (j1 < HIDD) s1 += row[j1];
  }
  float* dst = part + (size_t)(c*BATCH + b)*HIDD;
  dst[tid] = s0;
  if (j1 < HIDD) dst[j1] = s1;
}

// ---- colsum stage 2: fold 8 partials -> sums[32][300] ----------------------
__global__ void t13_colsum_comb(const float* __restrict__ part,
                                float* __restrict__ sums){
  int idx = blockIdx.x*256 + threadIdx.x;   // b*300 + j
  if (idx >= BATCH*HIDD) return;
  float s = 0.f;
  for (int c = 0; c < 8; c++) s += part[(size_t)c*BATCH*HIDD + idx];
  sums[idx] = s;
}

// ---- classifier GEMM, split-K=4 --------------------------------------------
__global__ __launch_bounds__(256) void t13_cls(
    const float* __restrict__ sums, const float* __restrict__ W,
    float* __restrict__ plog){
  int gid = blockIdx.x*256 + threadIdx.x;
  if (gid >= CLS_KS*BATCH*NCLS) return;
  int c = gid / (BATCH*NCLS);
  int rem = gid - c*(BATCH*NCLS);
  int m = rem / NCLS, n = rem - m*NCLS;
  const float* arow = sums + m*HIDD + c*CLS_KC;
  const float* wcol = W + (size_t)c*CLS_KC*NCLS + n;
  float acc = 0.f;
  #pragma unroll 5
  for (int k = 0; k < CLS_KC; k++)
    acc = fmaf(arow[k], wcol[(size_t)k*NCLS], acc);
  plog[gid] = acc;
}

// ---------------- classifier head: LayerNorm(ddof=1) + softmax -> fp32 -----
__device__ __forceinline__ float t10_bsum(float val, float* red){
  for (int off=32; off; off>>=1) val += __shfl_down(val, off);
  __syncthreads();
  if ((threadIdx.x & 63)==0) red[threadIdx.x>>6] = val;
  __syncthreads();
  return red[0]+red[1]+red[2]+red[3];
}
__device__ __forceinline__ float t10_bmax(float val, float* red){
  for (int off=32; off; off>>=1) val = fmaxf(val, __shfl_down(val, off));
  __syncthreads();
  if ((threadIdx.x & 63)==0) red[threadIdx.x>>6] = val;
  __syncthreads();
  return fmaxf(fmaxf(red[0],red[1]), fmaxf(red[2],red[3]));
}

__global__ __launch_bounds__(256) void t10_final(
                  const float* __restrict__ plog,
                  const float* __restrict__ gf, const float* __restrict__ bff,
                  float* __restrict__ outp){
  __shared__ float red[4];
  int b = blockIdx.x, tid = threadIdx.x;
  size_t base = (size_t)b*NCLS;
  float v[4];
  float s = 0.f, sq = 0.f;
  for (int t=0;t<4;t++){
    int j = tid + t*256;
    float x = 0.f;
    if (j < NCLS){
      for (int c=0;c<CLS_KS;c++) x += plog[(size_t)c*BATCH*NCLS + base + j];
    }
    v[t] = x; s += x; sq += x*x;
  }
  s  = t10_bsum(s, red);
  sq = t10_bsum(sq, red);
  float mu  = s * (1.0f/NCLS);
  float var = (sq - (float)NCLS*mu*mu) * (1.0f/(NCLS-1));
  float rstd = rsqrtf(var + 1e-8f);
  float g = gf[0], be = bff[0];
  float y[4]; float mx = -1e30f;
  for (int t=0;t<4;t++){
    int j = tid + t*256;
    y[t] = g*(v[t]-mu)*rstd + be;
    if (j < NCLS) mx = fmaxf(mx, y[t]);
  }
  mx = t10_bmax(mx, red);
  float p[4]; float es = 0.f;
  for (int t=0;t<4;t++){
    int j = tid + t*256;
    p[t] = (j < NCLS) ? __expf(y[t]-mx) : 0.f;
    es += p[t];
  }
  es = t10_bsum(es, red);
  float inv = 1.0f/es;
  for (int t=0;t<4;t++){
    int j = tid + t*256;
    if (j < NCLS) outp[base+j] = p[t]*inv;
  }
}

// ---------------------------------------------------------------------------
extern "C" void kernel_launch(void* const* d_in, const int* in_sizes, int n_in,
                              void* d_out, int out_size, void* d_ws, size_t ws_size,
                              hipStream_t stream){
  const int*   toks = (const int*)d_in[0];
  const float* emb  = (const float*)d_in[1];
  const float* WQ   = (const float*)d_in[2];
  const float* WK   = (const float*)d_in[3];
  const float* WV   = (const float*)d_in[4];
  const float* WO   = (const float*)d_in[5];
  const float* W1   = (const float*)d_in[6];
  const float* b1   = (const float*)d_in[7];
  const float* W2   = (const float*)d_in[8];
  const float* b2   = (const float*)d_in[9];
  const float* g1   = (const float*)d_in[10];
  const float* be1  = (const float*)d_in[11];
  const float* g2   = (const float*)d_in[12];
  const float* be2  = (const float*)d_in[13];
  const float* Vd   = (const float*)d_in[14];
  const float* gf   = (const float*)d_in[15];
  const float* bff  = (const float*)d_in[16];
  float* outp = (float*)d_out;

  // fp32 buffers
  float* acc    = (float*)d_ws;                         // [BSQ][300]
  float* xn     = acc    + (size_t)BSQ*HIDD;            // [BSQ][300]
  float* outb   = xn     + (size_t)BSQ*HIDD;            // [BSQ][300]
  float* tmp    = outb   + (size_t)BSQ*HIDD;            // [BSQ][300]
  float* qkv    = tmp    + (size_t)BSQ*HIDD;            // [BSQ][192]
  float* sums   = qkv    + (size_t)BSQ*192;             // [32][300]
  float* logits = sums   + BATCH*HIDD;                  // [32][1000] (unused)
  // attention partials alias tmp (dead during attention)
  float* pp     = tmp;
  float* ps     = tmp + (size_t)NSPLIT*BSQ*64;
  // bf16 buffers
  short* acc_bf = (short*)(logits + BATCH*NCLS);        // [BSQ][320]
  short* xn_bf  = acc_bf + (size_t)BSQ*320;             // [BSQ][320]
  short* aat_bf = xn_bf  + (size_t)BSQ*320;             // [BSQ][64]
  short* ff1_bf = aat_bf + (size_t)BSQ*64;              // [BSQ][1216]
  // bf16 weights
  short* wqkv = ff1_bf + (size_t)BSQ*1216;              // [6][192][320]
  short* wo   = wqkv + (size_t)6*192*320;               // [6][320][64]
  short* w1t  = wo   + (size_t)6*320*64;                // [6][1216][320]
  short* w2t  = w1t  + (size_t)6*1216*320;              // [6][320][1216]
  // classifier-tail fp32 buffers
  float* cspart = (float*)(w2t + (size_t)6*320*1216);   // [8][32][300]
  float* plog   = cspart + (size_t)8*BATCH*HIDD;        // [4][32][1000]

  {
    int tq = 6*64*320;
    prep_w<<<(tq+255)/256,256,0,stream>>>(WQ, wqkv, 300, 64, 320, 64, 0,   19200, 61440, tq, 1);
    prep_w<<<(tq+255)/256,256,0,stream>>>(WK, wqkv, 300, 64, 320, 64, 64,  19200, 61440, tq, 1);
    prep_w<<<(tq+255)/256,256,0,stream>>>(WV, wqkv, 300, 64, 320, 64, 128, 19200, 61440, tq, 1);
    int to = 6*320*64;
    prep_w<<<(to+255)/256,256,0,stream>>>(WO, wo, 64, 300, 64, 320, 0, 19200, 20480, to, 0);
    int t1 = 6*1216*320;
    prep_w<<<(t1+255)/256,256,0,stream>>>(W1, w1t, 300, 1200, 320, 1216, 0, 360000, 389120, t1, 0);
    int t2 = 6*320*1216;
    prep_w<<<(t2+255)/256,256,0,stream>>>(W2, w2t, 1200, 300, 1216, 320, 0, 360000, 389120, t2, 0);
  }

  t10_embed<<<(BSQ*320+255)/256, 256, 0, stream>>>(toks, emb, acc, acc_bf);

  for (int l = 0; l < NLAYERS; l++){
    mm_a16<<<256*3,256,0,stream>>>(acc_bf, wqkv + (size_t)l*61440, nullptr, qkv, nullptr,
                                   BSQ, 192, 320, 0, 3, 0);
    t14_attn<<<BATCH*NHEAD*NSPLIT, 256, 0, stream>>>(qkv, toks, pp, ps);
    t12_attn_comb<<<(BSQ*8)/256, 256, 0, stream>>>(pp, ps, aat_bf);
    mm_a16<<<256*5,256,0,stream>>>(aat_bf, wo + (size_t)l*20480, nullptr, tmp, nullptr,
                                   BSQ, 300, 64, 0, 5, 0);
    t10_addnorm<<<BSQ,256,0,stream>>>(tmp, acc, xn, xn_bf, nullptr, nullptr, g1, be1, l);
    mm_a16<<<256*19,256,0,stream>>>(xn_bf, w1t + (size_t)l*389120, b1 + (size_t)l*FFD,
                                    nullptr, ff1_bf, BSQ, 1200, 320, 1216, 19, 1);
    mm_a16<<<256*5,256,0,stream>>>(ff1_bf, w2t + (size_t)l*389120, b2 + (size_t)l*HIDD,
                                   tmp, nullptr, BSQ, 300, 1216, 0, 5, 0);
    t10_addnorm<<<BSQ,256,0,stream>>>(tmp, xn, outb, nullptr, acc, acc_bf, g2, be2, l);
  }

  t13_colsum_part<<<BATCH*8, 256, 0, stream>>>(outb, cspart);
  t13_colsum_comb<<<(BATCH*HIDD+255)/256, 256, 0, stream>>>(cspart, sums);
  t13_cls<<<(CLS_KS*BATCH*NCLS)/256, 256, 0, stream>>>(sums, Vd, plog);
  t10_final<<<BATCH, 256, 0, stream>>>(plog, gf, bff, outp);

  hipStreamCaptureStatus cs = hipStreamCaptureStatusNone;
  hipStreamIsCapturing(stream, &cs);
  if (cs == hipStreamCaptureStatusNone){
    hipError_t e_sync = hipStreamSynchronize(stream);
    float ho[4] = {-1,-1,-1,-1};
    hipMemcpy(ho, d_out, 16, hipMemcpyDeviceToHost);
    fprintf(stderr, "[t14] sync=%s out[0..3]=%g,%g,%g,%g\n",
            hipGetErrorString(e_sync), ho[0], ho[1], ho[2], ho[3]);
    fflush(stderr);
  }
}